// Round 14
// baseline (52.053 us; speedup 1.0000x reference)
//
#include <hip/hip_runtime.h>
#include <hip/hip_bf16.h>

#define BB  4
#define CC  128
#define ICH 64
#define NN  4096
#define SS  8            // KV split factor
#define KSPLIT (NN / SS) // 512 keys per block
#define MT (KSPLIT / 64) // 8 key-tiles per block

typedef __attribute__((ext_vector_type(4)))  float f32x4;
typedef __attribute__((ext_vector_type(16))) float f32x16;
typedef __attribute__((ext_vector_type(8)))  short bf16x8;
typedef __attribute__((ext_vector_type(4)))  unsigned u32x4;
typedef unsigned short u16;

static __device__ __forceinline__ f32x16 mfma32(bf16x8 a, bf16x8 b, f32x16 c) {
  return __builtin_amdgcn_mfma_f32_32x32x16_bf16(a, b, c, 0, 0, 0);
}
static __device__ __forceinline__ f32x4 mfma16(bf16x8 a, bf16x8 b, f32x4 c) {
  return __builtin_amdgcn_mfma_f32_16x16x32_bf16(a, b, c, 0, 0, 0);
}
static __device__ __forceinline__ u16 f2bf(float f) {
  __hip_bfloat16 h = __float2bfloat16(f);
  return *reinterpret_cast<u16*>(&h);
}
static __device__ __forceinline__ float bf2f(u16 u) {
  union { unsigned int i; float f; } v; v.i = ((unsigned int)u) << 16; return v.f;
}
static __device__ __forceinline__ void gl_lds16(const void* g, void* l) {
  __builtin_amdgcn_global_load_lds((const __attribute__((address_space(1))) void*)g,
                                   (__attribute__((address_space(3))) void*)l, 16, 0, 0);
}
static __device__ __forceinline__ f32x16 zero16() {
  f32x16 v;
#pragma unroll
  for (int i = 0; i < 16; ++i) v[i] = 0.f;
  return v;
}
static __device__ __forceinline__ unsigned cvtpk(float lo, float hi_) {
  unsigned r;
  asm("v_cvt_pk_bf16_f32 %0, %1, %2" : "=v"(r) : "v"(lo), "v"(hi_));
  return r;
}
static __device__ __forceinline__ void pl32swap(unsigned &a, unsigned &b) {
  asm("v_permlane32_swap_b32 %0, %1" : "+v"(a), "+v"(b));
}
static __device__ __forceinline__ bf16x8 frag4(unsigned w0, unsigned w1,
                                               unsigned w2, unsigned w3) {
  union { u32x4 w; bf16x8 h; } u;
  u.w[0] = w0; u.w[1] = w1; u.w[2] = w2; u.w[3] = w3;
  return u.h;
}

// ---------------- Kernel 1: projections via MFMA (R13 verbatim — validated) ---------
// grid: BB * (NN/32) = 512 blocks, 384 threads (6 waves).
__global__ __launch_bounds__(384) void proj_kernel(
    const float* __restrict__ x,
    const float* __restrict__ gw, const float* __restrict__ gb,
    const float* __restrict__ tw, const float* __restrict__ tb,
    const float* __restrict__ pw, const float* __restrict__ pb,
    u16* __restrict__ th, u16* __restrict__ ph, u16* __restrict__ gt)
{
  __shared__ __align__(16) float xs[CC * 32];   // [c][32 n], 128B rows
  const int t = threadIdx.x, wave = t / 64, lane = t & 63;
  const int l31 = lane & 31, hi = lane >> 5;
  const int b  = blockIdx.x >> 7;
  const int n0 = (blockIdx.x & 127) << 5;

  for (int idx = t; idx < CC * 8; idx += 384) {   // 1024 float4 chunks
    const int c = idx >> 3, n4 = idx & 7;
    *(float4*)&xs[c * 32 + n4 * 4] =
        *(const float4*)(x + ((size_t)(b * CC + c) << 12) + n0 + n4 * 4);
  }

  const int pt  = wave >> 1;
  const int ic0 = (wave & 1) << 5;
  const float* wsel = (pt == 0) ? gw : (pt == 1) ? tw : pw;

  bf16x8 wfrag[8];
  {
    const float* wrow = wsel + (ic0 + l31) * CC;
#pragma unroll
    for (int ks = 0; ks < 8; ++ks) {
      float4 a = *(const float4*)(wrow + ks * 16 + hi * 8);
      float4 c = *(const float4*)(wrow + ks * 16 + hi * 8 + 4);
      wfrag[ks] = frag4(cvtpk(a.x, a.y), cvtpk(a.z, a.w),
                        cvtpk(c.x, c.y), cvtpk(c.z, c.w));
    }
  }
  __syncthreads();

  f32x16 acc = zero16();
  if (pt == 0) {
#pragma unroll
    for (int ks = 0; ks < 8; ++ks) {
      const float* xp = xs + (ks * 16 + hi * 8) * 32 + l31;
      bf16x8 xf = frag4(cvtpk(xp[0], xp[32]),   cvtpk(xp[64], xp[96]),
                        cvtpk(xp[128], xp[160]), cvtpk(xp[192], xp[224]));
      acc = mfma32(wfrag[ks], xf, acc);
    }
#pragma unroll
    for (int reg = 0; reg < 16; ++reg) {
      const int ic = ic0 + (reg & 3) + 8 * (reg >> 2) + 4 * hi;
      gt[((size_t)(b * ICH + ic)) * NN + n0 + l31] = f2bf(acc[reg] + gb[ic]);
    }
  } else {
#pragma unroll
    for (int ks = 0; ks < 8; ++ks) {
      const float* xp = xs + (ks * 16 + hi * 8) * 32 + l31;
      bf16x8 xf = frag4(cvtpk(xp[0], xp[32]),   cvtpk(xp[64], xp[96]),
                        cvtpk(xp[128], xp[160]), cvtpk(xp[192], xp[224]));
      acc = mfma32(xf, wfrag[ks], acc);
    }
    u16* dst = (pt == 1) ? th : ph;
    const float bias = (pt == 1) ? tb[ic0 + l31] : pb[ic0 + l31];
#pragma unroll
    for (int reg = 0; reg < 16; ++reg) {
      const int n = n0 + (reg & 3) + 8 * (reg >> 2) + 4 * hi;
      dst[((size_t)(b * NN + n)) * ICH + ic0 + l31] = f2bf(acc[reg] + bias);
    }
  }
}

// per-chunk body: compile-time c so all addressing folds to constants
#define CHUNK(c)                                                               \
  {                                                                            \
    bf16x8 pf4[4];                                                             \
    _Pragma("unroll")                                                          \
    for (int ks = 0; ks < 4; ++ks)                                             \
      pf4[ks] = *(const bf16x8*)(phb + ((c) * 32 + l31) * 128 +                \
                                 ((ks * 32 + hi * 16) ^ swz));                 \
    f32x16 sacc = zero16();                                                    \
    __builtin_amdgcn_s_setprio(1);                                             \
    _Pragma("unroll")                                                          \
    for (int ks = 0; ks < 4; ++ks) sacc = mfma32(pf4[ks], aq[ks], sacc);       \
    __builtin_amdgcn_s_setprio(0);                                             \
    bf16x8 gA0 = *(const bf16x8*)(gtb + (0 * 32 + l31) * 128 +                 \
                                  (((c) * 64 + 0 + hi * 16) ^ swz));           \
    bf16x8 gA1 = *(const bf16x8*)(gtb + (0 * 32 + l31) * 128 +                 \
                                  (((c) * 64 + 32 + hi * 16) ^ swz));          \
    unsigned pk[8];                                                            \
    _Pragma("unroll")                                                          \
    for (int km = 0; km < 2; ++km) {                                           \
      unsigned P[4];                                                           \
      _Pragma("unroll")                                                        \
      for (int j = 0; j < 4; ++j) {                                            \
        float e0 = __expf(sacc[km * 8 + 2 * j]     - 8.0f);                    \
        float e1 = __expf(sacc[km * 8 + 2 * j + 1] - 8.0f);                    \
        Lpa += e0; Lpb += e1;                                                  \
        P[j] = cvtpk(e0, e1);                                                  \
      }                                                                        \
      pl32swap(P[0], P[2]); pl32swap(P[1], P[3]);                              \
      pk[km * 4 + 0] = P[0]; pk[km * 4 + 1] = P[1];                            \
      pk[km * 4 + 2] = P[2]; pk[km * 4 + 3] = P[3];                            \
    }                                                                          \
    bf16x8 pB0 = frag4(pk[0], pk[1], pk[2], pk[3]);                            \
    bf16x8 pB1 = frag4(pk[4], pk[5], pk[6], pk[7]);                            \
    __builtin_amdgcn_s_setprio(1);                                             \
    yacc[0] = mfma32(gA0, pB0, yacc[0]);                                       \
    yacc[0] = mfma32(gA1, pB1, yacc[0]);                                       \
    bf16x8 gB0 = *(const bf16x8*)(gtb + (1 * 32 + l31) * 128 +                 \
                                  (((c) * 64 + 0 + hi * 16) ^ swz));           \
    bf16x8 gB1 = *(const bf16x8*)(gtb + (1 * 32 + l31) * 128 +                 \
                                  (((c) * 64 + 32 + hi * 16) ^ swz));          \
    yacc[1] = mfma32(gB0, pB0, yacc[1]);                                       \
    yacc[1] = mfma32(gB1, pB1, yacc[1]);                                       \
    __builtin_amdgcn_s_setprio(0);                                             \
  }

// ---------------- Kernel 2: flash attention, wave-dephased chunk order --------------
// grid: BB * (NN/128) * SS = 1024 blocks, 256 threads (4 waves x 32 query rows)
__global__ __launch_bounds__(256, 4) void attn_kernel(
    const u16* __restrict__ thp, const u16* __restrict__ php,
    const u16* __restrict__ gtp, u16* __restrict__ yp, float* __restrict__ Lq)
{
  __shared__ __align__(16) u16 ph_s[2][4096];  // [buf][64 keys][64 ic], 128B rows, swz
  __shared__ __align__(16) u16 gt_s[2][4096];  // [buf][64 ic][64 keys], 128B rows, swz

  const int t    = threadIdx.x;
  const int wave = t >> 6, lane = t & 63;
  const int l31  = lane & 31, hi = lane >> 5;
  const int bid  = blockIdx.x;
  const int s    = bid & 7;
  const int rb   = (bid >> 3) & 31;
  const int b    = bid >> 8;
  const int nw   = rb * 128 + wave * 32;      // wave's first query row
  const size_t bbase = (size_t)b * NN * ICH;

  const int swz  = (l31 & 7) << 4;
  const int koff = 16 * ((lane & 7) ^ (lane >> 3));
  const int flip = (bid ^ wave) & 1;          // de-phase: half the waves swap chunk order

  bf16x8 aq[4];
#pragma unroll
  for (int ks = 0; ks < 4; ++ks)
    aq[ks] = *(const bf16x8*)(thp + bbase + (size_t)(nw + l31) * ICH + ks * 16 + hi * 8);

  f32x16 yacc[2];
  yacc[0] = zero16(); yacc[1] = zero16();
  float Lpa = 0.f, Lpb = 0.f;

  const char* ph_g = (const char*)php + bbase * 2;
  const char* gt_g = (const char*)gtp + (size_t)b * ICH * NN * 2;
  const int m_start = s * KSPLIT;

  auto stage = [&](int mt, int buf) {
    const int m0 = m_start + mt * 64;
#pragma unroll
    for (int u = 0; u < 2; ++u) {
      const int kk = wave * 2 + u;
      const int row = kk * 8 + (lane >> 3);
      gl_lds16(ph_g + (size_t)(m0 + row) * 128 + koff, (char*)ph_s[buf] + kk * 1024);
      gl_lds16(gt_g + (size_t)row * (NN * 2) + m0 * 2 + koff, (char*)gt_s[buf] + kk * 1024);
    }
  };

  stage(0, 0);
  for (int mt = 0; mt < MT; ++mt) {
    __syncthreads();                     // staged tile mt visible (vmcnt drained)
    if (mt + 1 < MT) stage(mt + 1, (mt + 1) & 1);
    const char* phb = (const char*)ph_s[mt & 1];
    const char* gtb = (const char*)gt_s[mt & 1];

    if (flip) { CHUNK(1); CHUNK(0); }
    else      { CHUNK(0); CHUNK(1); }
  }

  float Lp = Lpa + Lpb;
  Lp += __shfl_xor(Lp, 32);

  const size_t pbase = ((size_t)s * BB + b) * NN;
  if (hi == 0) Lq[pbase + nw + l31] = Lp;

  const size_t qg = pbase + nw + l31;
#pragma unroll
  for (int ci = 0; ci < 2; ++ci)
#pragma unroll
    for (int rg = 0; rg < 4; ++rg) {
      u16 o4[4];
#pragma unroll
      for (int j = 0; j < 4; ++j) o4[j] = f2bf(yacc[ci][rg * 4 + j]);
      *(unsigned long long*)(yp + qg * ICH + ci * 32 + 8 * rg + 4 * hi) =
          *(unsigned long long*)o4;
    }
}

// ---------------- Kernel 3: combine partials, out = W.y + Wb + x (R13 verbatim) -----
// grid: BB * (NN/32) = 512 blocks, 512 threads (8 waves, 16x16x32 MFMA)
__global__ __launch_bounds__(512) void out_kernel(
    const float* __restrict__ x, const float* __restrict__ Ww,
    const float* __restrict__ Wb, const u16* __restrict__ yp,
    const float* __restrict__ Lq, float* __restrict__ out)
{
  __shared__ float ysf[2][32][68];   // f32 half-sums, padded rows
  __shared__ float dens[2][32];
  const int t = threadIdx.x, lane = t & 63;
  const int wave = t >> 6;
  const int l15 = lane & 15, kq = lane >> 4;   // 16x16 fragment coords
  const int b  = blockIdx.x >> 7;
  const int n0 = (blockIdx.x & 127) << 5;

  {
    const int i8 = t & 7, sh = (t >> 3) & 1, n = t >> 4;
    float num[8];
#pragma unroll
    for (int j = 0; j < 8; ++j) num[j] = 0.f;
#pragma unroll
    for (int si = 0; si < 4; ++si) {
      const int s = sh * 4 + si;
      bf16x8 v = *(const bf16x8*)(yp + (((size_t)s * BB + b) * NN + n0 + n) * ICH + i8 * 8);
#pragma unroll
      for (int j = 0; j < 8; ++j) num[j] += bf2f((u16)v[j]);
    }
    *(float4*)&ysf[sh][n][i8 * 8]     = make_float4(num[0], num[1], num[2], num[3]);
    *(float4*)&ysf[sh][n][i8 * 8 + 4] = make_float4(num[4], num[5], num[6], num[7]);
    if (i8 == 0) {
      float den = 0.f;
#pragma unroll
      for (int si = 0; si < 4; ++si)
        den += Lq[((size_t)(sh * 4 + si) * BB + b) * NN + n0 + n];
      dens[sh][n] = den;
    }
  }
  __syncthreads();

  const int c0 = wave * 16;
  bf16x8 wfr[2];
#pragma unroll
  for (int kt = 0; kt < 2; ++kt) {
    const float* wp = Ww + (c0 + l15) * ICH + kt * 32 + kq * 8;
    float4 w0 = *(const float4*)wp, w1 = *(const float4*)(wp + 4);
    wfr[kt] = frag4(cvtpk(w0.x, w0.y), cvtpk(w0.z, w0.w),
                    cvtpk(w1.x, w1.y), cvtpk(w1.z, w1.w));
  }
#pragma unroll
  for (int nh = 0; nh < 2; ++nh) {
    const int n = nh * 16 + l15;
    const float rd = 1.f / (dens[0][n] + dens[1][n]);
    f32x4 acc = {0.f, 0.f, 0.f, 0.f};
#pragma unroll
    for (int kt = 0; kt < 2; ++kt) {
      const int base = kt * 32 + kq * 8;
      float4 a0 = *(const float4*)&ysf[0][n][base];
      float4 a1 = *(const float4*)&ysf[0][n][base + 4];
      float4 b0 = *(const float4*)&ysf[1][n][base];
      float4 b1 = *(const float4*)&ysf[1][n][base + 4];
      bf16x8 bfr = frag4(cvtpk((a0.x + b0.x) * rd, (a0.y + b0.y) * rd),
                         cvtpk((a0.z + b0.z) * rd, (a0.w + b0.w) * rd),
                         cvtpk((a1.x + b1.x) * rd, (a1.y + b1.y) * rd),
                         cvtpk((a1.z + b1.z) * rd, (a1.w + b1.w) * rd));
      acc = mfma16(wfr[kt], bfr, acc);
    }
#pragma unroll
    for (int reg = 0; reg < 4; ++reg) {
      const int c = c0 + kq * 4 + reg;
      size_t o = ((size_t)(b * CC + c) << 12) + n0 + nh * 16 + l15;
      out[o] = acc[reg] + Wb[c] + x[o];
    }
  }
}

extern "C" void kernel_launch(void* const* d_in, const int* in_sizes, int n_in,
                              void* d_out, int out_size, void* d_ws, size_t ws_size,
                              hipStream_t stream) {
  const float* x  = (const float*)d_in[0];
  const float* gw = (const float*)d_in[1];
  const float* gb = (const float*)d_in[2];
  const float* tw = (const float*)d_in[3];
  const float* tb = (const float*)d_in[4];
  const float* pw = (const float*)d_in[5];
  const float* pb = (const float*)d_in[6];
  const float* Ww = (const float*)d_in[7];
  const float* Wb = (const float*)d_in[8];
  float* out = (float*)d_out;

  char* ws = (char*)d_ws;
  u16*   th = (u16*)(ws);                      // 2MB
  u16*   ph = (u16*)(ws + (2ull << 20));       // 2MB
  u16*   gt = (u16*)(ws + (4ull << 20));       // 2MB
  u16*   yp = (u16*)(ws + (6ull << 20));       // SS*B*N*IC bf16 = 16MB
  float* Lq = (float*)(ws + (22ull << 20));    // SS*B*N f32 = 512KB

  proj_kernel<<<512, 384, 0, stream>>>(x, gw, gb, tw, tb, pw, pb, th, ph, gt);
  attn_kernel<<<BB * (NN / 128) * SS, 256, 0, stream>>>(th, ph, gt, yp, Lq);
  out_kernel<<<512, 512, 0, stream>>>(x, Ww, Wb, yp, Lq, out);
}

// Round 15
// 50.312 us; speedup vs baseline: 1.0346x; 1.0346x over previous
//
#include <hip/hip_runtime.h>
#include <hip/hip_bf16.h>

#define BB  4
#define CC  128
#define ICH 64
#define NN  4096
#define SS  8            // KV split factor
#define KSPLIT (NN / SS) // 512 keys per block
#define MT (KSPLIT / 64) // 8 key-tiles per block

typedef __attribute__((ext_vector_type(4)))  float f32x4;
typedef __attribute__((ext_vector_type(16))) float f32x16;
typedef __attribute__((ext_vector_type(8)))  short bf16x8;
typedef __attribute__((ext_vector_type(4)))  unsigned u32x4;
typedef unsigned short u16;

static __device__ __forceinline__ f32x16 mfma32(bf16x8 a, bf16x8 b, f32x16 c) {
  return __builtin_amdgcn_mfma_f32_32x32x16_bf16(a, b, c, 0, 0, 0);
}
static __device__ __forceinline__ f32x4 mfma16(bf16x8 a, bf16x8 b, f32x4 c) {
  return __builtin_amdgcn_mfma_f32_16x16x32_bf16(a, b, c, 0, 0, 0);
}
static __device__ __forceinline__ u16 f2bf(float f) {
  __hip_bfloat16 h = __float2bfloat16(f);
  return *reinterpret_cast<u16*>(&h);
}
static __device__ __forceinline__ float bf2f(u16 u) {
  union { unsigned int i; float f; } v; v.i = ((unsigned int)u) << 16; return v.f;
}
static __device__ __forceinline__ void gl_lds16(const void* g, void* l) {
  __builtin_amdgcn_global_load_lds((const __attribute__((address_space(1))) void*)g,
                                   (__attribute__((address_space(3))) void*)l, 16, 0, 0);
}
static __device__ __forceinline__ f32x16 zero16() {
  f32x16 v;
#pragma unroll
  for (int i = 0; i < 16; ++i) v[i] = 0.f;
  return v;
}
static __device__ __forceinline__ unsigned cvtpk(float lo, float hi_) {
  unsigned r;
  asm("v_cvt_pk_bf16_f32 %0, %1, %2" : "=v"(r) : "v"(lo), "v"(hi_));
  return r;
}
static __device__ __forceinline__ void pl32swap(unsigned &a, unsigned &b) {
  asm("v_permlane32_swap_b32 %0, %1" : "+v"(a), "+v"(b));
}
static __device__ __forceinline__ bf16x8 frag4(unsigned w0, unsigned w1,
                                               unsigned w2, unsigned w3) {
  union { u32x4 w; bf16x8 h; } u;
  u.w[0] = w0; u.w[1] = w1; u.w[2] = w2; u.w[3] = w3;
  return u.h;
}

// ---------------- Kernel 1: projections via MFMA (R13 verbatim — validated) ---------
// grid: BB * (NN/32) = 512 blocks, 384 threads (6 waves).
__global__ __launch_bounds__(384) void proj_kernel(
    const float* __restrict__ x,
    const float* __restrict__ gw, const float* __restrict__ gb,
    const float* __restrict__ tw, const float* __restrict__ tb,
    const float* __restrict__ pw, const float* __restrict__ pb,
    u16* __restrict__ th, u16* __restrict__ ph, u16* __restrict__ gt)
{
  __shared__ __align__(16) float xs[CC * 32];   // [c][32 n], 128B rows
  const int t = threadIdx.x, wave = t / 64, lane = t & 63;
  const int l31 = lane & 31, hi = lane >> 5;
  const int b  = blockIdx.x >> 7;
  const int n0 = (blockIdx.x & 127) << 5;

  for (int idx = t; idx < CC * 8; idx += 384) {   // 1024 float4 chunks
    const int c = idx >> 3, n4 = idx & 7;
    *(float4*)&xs[c * 32 + n4 * 4] =
        *(const float4*)(x + ((size_t)(b * CC + c) << 12) + n0 + n4 * 4);
  }

  const int pt  = wave >> 1;
  const int ic0 = (wave & 1) << 5;
  const float* wsel = (pt == 0) ? gw : (pt == 1) ? tw : pw;

  bf16x8 wfrag[8];
  {
    const float* wrow = wsel + (ic0 + l31) * CC;
#pragma unroll
    for (int ks = 0; ks < 8; ++ks) {
      float4 a = *(const float4*)(wrow + ks * 16 + hi * 8);
      float4 c = *(const float4*)(wrow + ks * 16 + hi * 8 + 4);
      wfrag[ks] = frag4(cvtpk(a.x, a.y), cvtpk(a.z, a.w),
                        cvtpk(c.x, c.y), cvtpk(c.z, c.w));
    }
  }
  __syncthreads();

  f32x16 acc = zero16();
  if (pt == 0) {
#pragma unroll
    for (int ks = 0; ks < 8; ++ks) {
      const float* xp = xs + (ks * 16 + hi * 8) * 32 + l31;
      bf16x8 xf = frag4(cvtpk(xp[0], xp[32]),   cvtpk(xp[64], xp[96]),
                        cvtpk(xp[128], xp[160]), cvtpk(xp[192], xp[224]));
      acc = mfma32(wfrag[ks], xf, acc);
    }
#pragma unroll
    for (int reg = 0; reg < 16; ++reg) {
      const int ic = ic0 + (reg & 3) + 8 * (reg >> 2) + 4 * hi;
      gt[((size_t)(b * ICH + ic)) * NN + n0 + l31] = f2bf(acc[reg] + gb[ic]);
    }
  } else {
#pragma unroll
    for (int ks = 0; ks < 8; ++ks) {
      const float* xp = xs + (ks * 16 + hi * 8) * 32 + l31;
      bf16x8 xf = frag4(cvtpk(xp[0], xp[32]),   cvtpk(xp[64], xp[96]),
                        cvtpk(xp[128], xp[160]), cvtpk(xp[192], xp[224]));
      acc = mfma32(xf, wfrag[ks], acc);
    }
    u16* dst = (pt == 1) ? th : ph;
    const float bias = (pt == 1) ? tb[ic0 + l31] : pb[ic0 + l31];
#pragma unroll
    for (int reg = 0; reg < 16; ++reg) {
      const int n = n0 + (reg & 3) + 8 * (reg >> 2) + 4 * hi;
      dst[((size_t)(b * NN + n)) * ICH + ic0 + l31] = f2bf(acc[reg] + bias);
    }
  }
}

// ---------------- Kernel 2: flash attention, counted-vmcnt pipeline (T4) ------------
// grid: BB * (NN/128) * SS = 1024 blocks, 256 threads (4 waves x 32 query rows)
// 2-tile-deep prefetch; per-tile wait is vmcnt(4) (4 newer loads stay in flight) —
// never drains to 0 in the main loop (R3..R14 used __syncthreads = full vmcnt(0)
// drain twice per tile; m233-style stall suspected as the ~35us plateau cause).
__global__ __launch_bounds__(256, 4) void attn_kernel(
    const u16* __restrict__ thp, const u16* __restrict__ php,
    const u16* __restrict__ gtp, u16* __restrict__ yp, float* __restrict__ Lq)
{
  __shared__ __align__(16) u16 ph_s[2][4096];  // [buf][64 keys][64 ic], 128B rows, swz
  __shared__ __align__(16) u16 gt_s[2][4096];  // [buf][64 ic][64 keys], 128B rows, swz

  const int t    = threadIdx.x;
  const int wave = t >> 6, lane = t & 63;
  const int l31  = lane & 31, hi = lane >> 5;
  const int bid  = blockIdx.x;
  const int s    = bid & 7;
  const int rb   = (bid >> 3) & 31;
  const int b    = bid >> 8;
  const int nw   = rb * 128 + wave * 32;      // wave's first query row
  const size_t bbase = (size_t)b * NN * ICH;

  const int swz  = (l31 & 7) << 4;
  const int koff = 16 * ((lane & 7) ^ (lane >> 3));

  bf16x8 aq[4];
#pragma unroll
  for (int ks = 0; ks < 4; ++ks)
    aq[ks] = *(const bf16x8*)(thp + bbase + (size_t)(nw + l31) * ICH + ks * 16 + hi * 8);

  f32x16 yacc[2];
  yacc[0] = zero16(); yacc[1] = zero16();
  float Lpa = 0.f, Lpb = 0.f;

  const char* ph_g = (const char*)php + bbase * 2;
  const char* gt_g = (const char*)gtp + (size_t)b * ICH * NN * 2;
  const int m_start = s * KSPLIT;

  // stage(): exactly 4 gl_lds per thread (uniform across all threads)
  auto stage = [&](int mt, int buf) {
    const int m0 = m_start + mt * 64;
#pragma unroll
    for (int u = 0; u < 2; ++u) {
      const int kk = wave * 2 + u;
      const int row = kk * 8 + (lane >> 3);
      gl_lds16(ph_g + (size_t)(m0 + row) * 128 + koff, (char*)ph_s[buf] + kk * 1024);
      gl_lds16(gt_g + (size_t)row * (NN * 2) + m0 * 2 + koff, (char*)gt_s[buf] + kk * 1024);
    }
  };

  stage(0, 0);
  stage(1, 1);
#pragma unroll
  for (int mt = 0; mt < MT; ++mt) {
    // wait for tile mt's 4 loads; tile mt+1's 4 (if any) remain in flight
    if (mt + 1 < MT) { asm volatile("s_waitcnt vmcnt(4)" ::: "memory"); }
    else             { asm volatile("s_waitcnt vmcnt(0)" ::: "memory"); }
    __builtin_amdgcn_s_barrier();        // all waves' tile-mt loads landed in LDS
    const char* phb = (const char*)ph_s[mt & 1];
    const char* gtb = (const char*)gt_s[mt & 1];

    // ---- QK for BOTH 32-key chunks (R13 body, unchanged) ----
    bf16x8 pf0[4];
#pragma unroll
    for (int ks = 0; ks < 4; ++ks)
      pf0[ks] = *(const bf16x8*)(phb + (0 * 32 + l31) * 128 +
                                 ((ks * 32 + hi * 16) ^ swz));
    f32x16 s0 = zero16(), s1 = zero16();
    __builtin_amdgcn_s_setprio(1);
    s0 = mfma32(pf0[0], aq[0], s0);
    s0 = mfma32(pf0[1], aq[1], s0);
    s0 = mfma32(pf0[2], aq[2], s0);
    s0 = mfma32(pf0[3], aq[3], s0);
    __builtin_amdgcn_s_setprio(0);
    bf16x8 pf1[4];
#pragma unroll
    for (int ks = 0; ks < 4; ++ks)
      pf1[ks] = *(const bf16x8*)(phb + (1 * 32 + l31) * 128 +
                                 ((ks * 32 + hi * 16) ^ swz));
    __builtin_amdgcn_s_setprio(1);
    s1 = mfma32(pf1[0], aq[0], s1);
    s1 = mfma32(pf1[1], aq[1], s1);
    s1 = mfma32(pf1[2], aq[2], s1);
    s1 = mfma32(pf1[3], aq[3], s1);
    __builtin_amdgcn_s_setprio(0);

    unsigned pk0[8], pk1[8];
#pragma unroll
    for (int km = 0; km < 2; ++km) {
      unsigned P[4], Q[4];
#pragma unroll
      for (int j = 0; j < 4; ++j) {
        float e0 = __expf(s0[km * 8 + 2 * j]     - 8.0f);
        float e1 = __expf(s0[km * 8 + 2 * j + 1] - 8.0f);
        float f0 = __expf(s1[km * 8 + 2 * j]     - 8.0f);
        float f1 = __expf(s1[km * 8 + 2 * j + 1] - 8.0f);
        Lpa += e0 + f0; Lpb += e1 + f1;
        P[j] = cvtpk(e0, e1);
        Q[j] = cvtpk(f0, f1);
      }
      pl32swap(P[0], P[2]); pl32swap(P[1], P[3]);
      pl32swap(Q[0], Q[2]); pl32swap(Q[1], Q[3]);
      pk0[km * 4 + 0] = P[0]; pk0[km * 4 + 1] = P[1];
      pk0[km * 4 + 2] = P[2]; pk0[km * 4 + 3] = P[3];
      pk1[km * 4 + 0] = Q[0]; pk1[km * 4 + 1] = Q[1];
      pk1[km * 4 + 2] = Q[2]; pk1[km * 4 + 3] = Q[3];
    }
    bf16x8 p00 = frag4(pk0[0], pk0[1], pk0[2], pk0[3]);
    bf16x8 p01 = frag4(pk0[4], pk0[5], pk0[6], pk0[7]);
    bf16x8 p10 = frag4(pk1[0], pk1[1], pk1[2], pk1[3]);
    bf16x8 p11 = frag4(pk1[4], pk1[5], pk1[6], pk1[7]);

    bf16x8 g00 = *(const bf16x8*)(gtb + (0 * 32 + l31) * 128 + ((0  + hi * 16) ^ swz));
    bf16x8 g01 = *(const bf16x8*)(gtb + (0 * 32 + l31) * 128 + ((32 + hi * 16) ^ swz));
    bf16x8 g10 = *(const bf16x8*)(gtb + (1 * 32 + l31) * 128 + ((0  + hi * 16) ^ swz));
    bf16x8 g11 = *(const bf16x8*)(gtb + (1 * 32 + l31) * 128 + ((32 + hi * 16) ^ swz));
    __builtin_amdgcn_s_setprio(1);
    yacc[0] = mfma32(g00, p00, yacc[0]);
    yacc[1] = mfma32(g10, p00, yacc[1]);
    yacc[0] = mfma32(g01, p01, yacc[0]);
    yacc[1] = mfma32(g11, p01, yacc[1]);
    __builtin_amdgcn_s_setprio(0);
    bf16x8 g02 = *(const bf16x8*)(gtb + (0 * 32 + l31) * 128 + ((64 + hi * 16) ^ swz));
    bf16x8 g03 = *(const bf16x8*)(gtb + (0 * 32 + l31) * 128 + ((96 + hi * 16) ^ swz));
    bf16x8 g12 = *(const bf16x8*)(gtb + (1 * 32 + l31) * 128 + ((64 + hi * 16) ^ swz));
    bf16x8 g13 = *(const bf16x8*)(gtb + (1 * 32 + l31) * 128 + ((96 + hi * 16) ^ swz));
    __builtin_amdgcn_s_setprio(1);
    yacc[0] = mfma32(g02, p10, yacc[0]);
    yacc[1] = mfma32(g12, p10, yacc[1]);
    yacc[0] = mfma32(g03, p11, yacc[0]);
    yacc[1] = mfma32(g13, p11, yacc[1]);
    __builtin_amdgcn_s_setprio(0);

    // all my LDS reads retired; barrier → whole block done reading buf[mt&1];
    // only then overwrite it with tile mt+2 (loads stay async past the barrier)
    asm volatile("s_waitcnt lgkmcnt(0)" ::: "memory");
    __builtin_amdgcn_s_barrier();
    if (mt + 2 < MT) stage(mt + 2, mt & 1);
  }

  float Lp = Lpa + Lpb;
  Lp += __shfl_xor(Lp, 32);

  const size_t pbase = ((size_t)s * BB + b) * NN;
  if (hi == 0) Lq[pbase + nw + l31] = Lp;

  const size_t qg = pbase + nw + l31;
#pragma unroll
  for (int ci = 0; ci < 2; ++ci)
#pragma unroll
    for (int rg = 0; rg < 4; ++rg) {
      u16 o4[4];
#pragma unroll
      for (int j = 0; j < 4; ++j) o4[j] = f2bf(yacc[ci][rg * 4 + j]);
      *(unsigned long long*)(yp + qg * ICH + ci * 32 + 8 * rg + 4 * hi) =
          *(unsigned long long*)o4;
    }
}

// ---------------- Kernel 3: combine partials, out = W.y + Wb + x (R13 verbatim) -----
// grid: BB * (NN/32) = 512 blocks, 512 threads (8 waves, 16x16x32 MFMA)
__global__ __launch_bounds__(512) void out_kernel(
    const float* __restrict__ x, const float* __restrict__ Ww,
    const float* __restrict__ Wb, const u16* __restrict__ yp,
    const float* __restrict__ Lq, float* __restrict__ out)
{
  __shared__ float ysf[2][32][68];   // f32 half-sums, padded rows
  __shared__ float dens[2][32];
  const int t = threadIdx.x, lane = t & 63;
  const int wave = t >> 6;
  const int l15 = lane & 15, kq = lane >> 4;   // 16x16 fragment coords
  const int b  = blockIdx.x >> 7;
  const int n0 = (blockIdx.x & 127) << 5;

  {
    const int i8 = t & 7, sh = (t >> 3) & 1, n = t >> 4;
    float num[8];
#pragma unroll
    for (int j = 0; j < 8; ++j) num[j] = 0.f;
#pragma unroll
    for (int si = 0; si < 4; ++si) {
      const int s = sh * 4 + si;
      bf16x8 v = *(const bf16x8*)(yp + (((size_t)s * BB + b) * NN + n0 + n) * ICH + i8 * 8);
#pragma unroll
      for (int j = 0; j < 8; ++j) num[j] += bf2f((u16)v[j]);
    }
    *(float4*)&ysf[sh][n][i8 * 8]     = make_float4(num[0], num[1], num[2], num[3]);
    *(float4*)&ysf[sh][n][i8 * 8 + 4] = make_float4(num[4], num[5], num[6], num[7]);
    if (i8 == 0) {
      float den = 0.f;
#pragma unroll
      for (int si = 0; si < 4; ++si)
        den += Lq[((size_t)(sh * 4 + si) * BB + b) * NN + n0 + n];
      dens[sh][n] = den;
    }
  }
  __syncthreads();

  const int c0 = wave * 16;
  bf16x8 wfr[2];
#pragma unroll
  for (int kt = 0; kt < 2; ++kt) {
    const float* wp = Ww + (c0 + l15) * ICH + kt * 32 + kq * 8;
    float4 w0 = *(const float4*)wp, w1 = *(const float4*)(wp + 4);
    wfr[kt] = frag4(cvtpk(w0.x, w0.y), cvtpk(w0.z, w0.w),
                    cvtpk(w1.x, w1.y), cvtpk(w1.z, w1.w));
  }
#pragma unroll
  for (int nh = 0; nh < 2; ++nh) {
    const int n = nh * 16 + l15;
    const float rd = 1.f / (dens[0][n] + dens[1][n]);
    f32x4 acc = {0.f, 0.f, 0.f, 0.f};
#pragma unroll
    for (int kt = 0; kt < 2; ++kt) {
      const int base = kt * 32 + kq * 8;
      float4 a0 = *(const float4*)&ysf[0][n][base];
      float4 a1 = *(const float4*)&ysf[0][n][base + 4];
      float4 b0 = *(const float4*)&ysf[1][n][base];
      float4 b1 = *(const float4*)&ysf[1][n][base + 4];
      bf16x8 bfr = frag4(cvtpk((a0.x + b0.x) * rd, (a0.y + b0.y) * rd),
                         cvtpk((a0.z + b0.z) * rd, (a0.w + b0.w) * rd),
                         cvtpk((a1.x + b1.x) * rd, (a1.y + b1.y) * rd),
                         cvtpk((a1.z + b1.z) * rd, (a1.w + b1.w) * rd));
      acc = mfma16(wfr[kt], bfr, acc);
    }
#pragma unroll
    for (int reg = 0; reg < 4; ++reg) {
      const int c = c0 + kq * 4 + reg;
      size_t o = ((size_t)(b * CC + c) << 12) + n0 + nh * 16 + l15;
      out[o] = acc[reg] + Wb[c] + x[o];
    }
  }
}

extern "C" void kernel_launch(void* const* d_in, const int* in_sizes, int n_in,
                              void* d_out, int out_size, void* d_ws, size_t ws_size,
                              hipStream_t stream) {
  const float* x  = (const float*)d_in[0];
  const float* gw = (const float*)d_in[1];
  const float* gb = (const float*)d_in[2];
  const float* tw = (const float*)d_in[3];
  const float* tb = (const float*)d_in[4];
  const float* pw = (const float*)d_in[5];
  const float* pb = (const float*)d_in[6];
  const float* Ww = (const float*)d_in[7];
  const float* Wb = (const float*)d_in[8];
  float* out = (float*)d_out;

  char* ws = (char*)d_ws;
  u16*   th = (u16*)(ws);                      // 2MB
  u16*   ph = (u16*)(ws + (2ull << 20));       // 2MB
  u16*   gt = (u16*)(ws + (4ull << 20));       // 2MB
  u16*   yp = (u16*)(ws + (6ull << 20));       // SS*B*N*IC bf16 = 16MB
  float* Lq = (float*)(ws + (22ull << 20));    // SS*B*N f32 = 512KB

  proj_kernel<<<512, 384, 0, stream>>>(x, gw, gb, tw, tb, pw, pb, th, ph, gt);
  attn_kernel<<<BB * (NN / 128) * SS, 256, 0, stream>>>(th, ph, gt, yp, Lq);
  out_kernel<<<512, 512, 0, stream>>>(x, Ww, Wb, yp, Lq, out);
}

// Round 16
// 50.290 us; speedup vs baseline: 1.0351x; 1.0004x over previous
//
#include <hip/hip_runtime.h>
#include <hip/hip_bf16.h>

#define BB  4
#define CC  128
#define ICH 64
#define NN  4096
#define SS  8            // KV split factor
#define KSPLIT (NN / SS) // 512 keys per block
#define MT (KSPLIT / 64) // 8 key-tiles per block

typedef __attribute__((ext_vector_type(4)))  float f32x4;
typedef __attribute__((ext_vector_type(16))) float f32x16;
typedef __attribute__((ext_vector_type(8)))  short bf16x8;
typedef __attribute__((ext_vector_type(4)))  unsigned u32x4;
typedef unsigned short u16;

static __device__ __forceinline__ f32x16 mfma32(bf16x8 a, bf16x8 b, f32x16 c) {
  return __builtin_amdgcn_mfma_f32_32x32x16_bf16(a, b, c, 0, 0, 0);
}
static __device__ __forceinline__ f32x4 mfma16(bf16x8 a, bf16x8 b, f32x4 c) {
  return __builtin_amdgcn_mfma_f32_16x16x32_bf16(a, b, c, 0, 0, 0);
}
static __device__ __forceinline__ u16 f2bf(float f) {
  __hip_bfloat16 h = __float2bfloat16(f);
  return *reinterpret_cast<u16*>(&h);
}
static __device__ __forceinline__ float bf2f(u16 u) {
  union { unsigned int i; float f; } v; v.i = ((unsigned int)u) << 16; return v.f;
}
static __device__ __forceinline__ void gl_lds16(const void* g, void* l) {
  __builtin_amdgcn_global_load_lds((const __attribute__((address_space(1))) void*)g,
                                   (__attribute__((address_space(3))) void*)l, 16, 0, 0);
}
static __device__ __forceinline__ f32x16 zero16() {
  f32x16 v;
#pragma unroll
  for (int i = 0; i < 16; ++i) v[i] = 0.f;
  return v;
}
static __device__ __forceinline__ unsigned cvtpk(float lo, float hi_) {
  unsigned r;
  asm("v_cvt_pk_bf16_f32 %0, %1, %2" : "=v"(r) : "v"(lo), "v"(hi_));
  return r;
}
static __device__ __forceinline__ void pl32swap(unsigned &a, unsigned &b) {
  asm("v_permlane32_swap_b32 %0, %1" : "+v"(a), "+v"(b));
}
static __device__ __forceinline__ bf16x8 frag4(unsigned w0, unsigned w1,
                                               unsigned w2, unsigned w3) {
  union { u32x4 w; bf16x8 h; } u;
  u.w[0] = w0; u.w[1] = w1; u.w[2] = w2; u.w[3] = w3;
  return u.h;
}

// ---------------- Kernel 1: projections via MFMA (R13 verbatim — validated) ---------
// grid: BB * (NN/32) = 512 blocks, 384 threads (6 waves).
__global__ __launch_bounds__(384) void proj_kernel(
    const float* __restrict__ x,
    const float* __restrict__ gw, const float* __restrict__ gb,
    const float* __restrict__ tw, const float* __restrict__ tb,
    const float* __restrict__ pw, const float* __restrict__ pb,
    u16* __restrict__ th, u16* __restrict__ ph, u16* __restrict__ gt)
{
  __shared__ __align__(16) float xs[CC * 32];   // [c][32 n], 128B rows
  const int t = threadIdx.x, wave = t / 64, lane = t & 63;
  const int l31 = lane & 31, hi = lane >> 5;
  const int b  = blockIdx.x >> 7;
  const int n0 = (blockIdx.x & 127) << 5;

  for (int idx = t; idx < CC * 8; idx += 384) {   // 1024 float4 chunks
    const int c = idx >> 3, n4 = idx & 7;
    *(float4*)&xs[c * 32 + n4 * 4] =
        *(const float4*)(x + ((size_t)(b * CC + c) << 12) + n0 + n4 * 4);
  }

  const int pt  = wave >> 1;
  const int ic0 = (wave & 1) << 5;
  const float* wsel = (pt == 0) ? gw : (pt == 1) ? tw : pw;

  bf16x8 wfrag[8];
  {
    const float* wrow = wsel + (ic0 + l31) * CC;
#pragma unroll
    for (int ks = 0; ks < 8; ++ks) {
      float4 a = *(const float4*)(wrow + ks * 16 + hi * 8);
      float4 c = *(const float4*)(wrow + ks * 16 + hi * 8 + 4);
      wfrag[ks] = frag4(cvtpk(a.x, a.y), cvtpk(a.z, a.w),
                        cvtpk(c.x, c.y), cvtpk(c.z, c.w));
    }
  }
  __syncthreads();

  f32x16 acc = zero16();
  if (pt == 0) {
#pragma unroll
    for (int ks = 0; ks < 8; ++ks) {
      const float* xp = xs + (ks * 16 + hi * 8) * 32 + l31;
      bf16x8 xf = frag4(cvtpk(xp[0], xp[32]),   cvtpk(xp[64], xp[96]),
                        cvtpk(xp[128], xp[160]), cvtpk(xp[192], xp[224]));
      acc = mfma32(wfrag[ks], xf, acc);
    }
#pragma unroll
    for (int reg = 0; reg < 16; ++reg) {
      const int ic = ic0 + (reg & 3) + 8 * (reg >> 2) + 4 * hi;
      gt[((size_t)(b * ICH + ic)) * NN + n0 + l31] = f2bf(acc[reg] + gb[ic]);
    }
  } else {
#pragma unroll
    for (int ks = 0; ks < 8; ++ks) {
      const float* xp = xs + (ks * 16 + hi * 8) * 32 + l31;
      bf16x8 xf = frag4(cvtpk(xp[0], xp[32]),   cvtpk(xp[64], xp[96]),
                        cvtpk(xp[128], xp[160]), cvtpk(xp[192], xp[224]));
      acc = mfma32(xf, wfrag[ks], acc);
    }
    u16* dst = (pt == 1) ? th : ph;
    const float bias = (pt == 1) ? tb[ic0 + l31] : pb[ic0 + l31];
#pragma unroll
    for (int reg = 0; reg < 16; ++reg) {
      const int n = n0 + (reg & 3) + 8 * (reg >> 2) + 4 * hi;
      dst[((size_t)(b * NN + n)) * ICH + ic0 + l31] = f2bf(acc[reg] + bias);
    }
  }
}

// ---------------- Kernel 2: flash attention, counted-vmcnt pipeline (T4) ------------
// grid: BB * (NN/128) * SS = 1024 blocks, 256 threads (4 waves x 32 query rows)
// 2-tile-deep prefetch; per-tile wait is vmcnt(4) (4 newer loads stay in flight) —
// never drains to 0 in the main loop (R3..R14 used __syncthreads = full vmcnt(0)
// drain twice per tile; m233-style stall suspected as the ~35us plateau cause).
__global__ __launch_bounds__(256, 4) void attn_kernel(
    const u16* __restrict__ thp, const u16* __restrict__ php,
    const u16* __restrict__ gtp, u16* __restrict__ yp, float* __restrict__ Lq)
{
  __shared__ __align__(16) u16 ph_s[2][4096];  // [buf][64 keys][64 ic], 128B rows, swz
  __shared__ __align__(16) u16 gt_s[2][4096];  // [buf][64 ic][64 keys], 128B rows, swz

  const int t    = threadIdx.x;
  const int wave = t >> 6, lane = t & 63;
  const int l31  = lane & 31, hi = lane >> 5;
  const int bid  = blockIdx.x;
  const int s    = bid & 7;
  const int rb   = (bid >> 3) & 31;
  const int b    = bid >> 8;
  const int nw   = rb * 128 + wave * 32;      // wave's first query row
  const size_t bbase = (size_t)b * NN * ICH;

  const int swz  = (l31 & 7) << 4;
  const int koff = 16 * ((lane & 7) ^ (lane >> 3));

  bf16x8 aq[4];
#pragma unroll
  for (int ks = 0; ks < 4; ++ks)
    aq[ks] = *(const bf16x8*)(thp + bbase + (size_t)(nw + l31) * ICH + ks * 16 + hi * 8);

  f32x16 yacc[2];
  yacc[0] = zero16(); yacc[1] = zero16();
  float Lpa = 0.f, Lpb = 0.f;

  const char* ph_g = (const char*)php + bbase * 2;
  const char* gt_g = (const char*)gtp + (size_t)b * ICH * NN * 2;
  const int m_start = s * KSPLIT;

  // stage(): exactly 4 gl_lds per thread (uniform across all threads)
  auto stage = [&](int mt, int buf) {
    const int m0 = m_start + mt * 64;
#pragma unroll
    for (int u = 0; u < 2; ++u) {
      const int kk = wave * 2 + u;
      const int row = kk * 8 + (lane >> 3);
      gl_lds16(ph_g + (size_t)(m0 + row) * 128 + koff, (char*)ph_s[buf] + kk * 1024);
      gl_lds16(gt_g + (size_t)row * (NN * 2) + m0 * 2 + koff, (char*)gt_s[buf] + kk * 1024);
    }
  };

  stage(0, 0);
  stage(1, 1);
#pragma unroll
  for (int mt = 0; mt < MT; ++mt) {
    // wait for tile mt's 4 loads; tile mt+1's 4 (if any) remain in flight
    if (mt + 1 < MT) { asm volatile("s_waitcnt vmcnt(4)" ::: "memory"); }
    else             { asm volatile("s_waitcnt vmcnt(0)" ::: "memory"); }
    __builtin_amdgcn_s_barrier();        // all waves' tile-mt loads landed in LDS
    const char* phb = (const char*)ph_s[mt & 1];
    const char* gtb = (const char*)gt_s[mt & 1];

    // ---- QK for BOTH 32-key chunks (R13 body, unchanged) ----
    bf16x8 pf0[4];
#pragma unroll
    for (int ks = 0; ks < 4; ++ks)
      pf0[ks] = *(const bf16x8*)(phb + (0 * 32 + l31) * 128 +
                                 ((ks * 32 + hi * 16) ^ swz));
    f32x16 s0 = zero16(), s1 = zero16();
    __builtin_amdgcn_s_setprio(1);
    s0 = mfma32(pf0[0], aq[0], s0);
    s0 = mfma32(pf0[1], aq[1], s0);
    s0 = mfma32(pf0[2], aq[2], s0);
    s0 = mfma32(pf0[3], aq[3], s0);
    __builtin_amdgcn_s_setprio(0);
    bf16x8 pf1[4];
#pragma unroll
    for (int ks = 0; ks < 4; ++ks)
      pf1[ks] = *(const bf16x8*)(phb + (1 * 32 + l31) * 128 +
                                 ((ks * 32 + hi * 16) ^ swz));
    __builtin_amdgcn_s_setprio(1);
    s1 = mfma32(pf1[0], aq[0], s1);
    s1 = mfma32(pf1[1], aq[1], s1);
    s1 = mfma32(pf1[2], aq[2], s1);
    s1 = mfma32(pf1[3], aq[3], s1);
    __builtin_amdgcn_s_setprio(0);

    unsigned pk0[8], pk1[8];
#pragma unroll
    for (int km = 0; km < 2; ++km) {
      unsigned P[4], Q[4];
#pragma unroll
      for (int j = 0; j < 4; ++j) {
        float e0 = __expf(s0[km * 8 + 2 * j]     - 8.0f);
        float e1 = __expf(s0[km * 8 + 2 * j + 1] - 8.0f);
        float f0 = __expf(s1[km * 8 + 2 * j]     - 8.0f);
        float f1 = __expf(s1[km * 8 + 2 * j + 1] - 8.0f);
        Lpa += e0 + f0; Lpb += e1 + f1;
        P[j] = cvtpk(e0, e1);
        Q[j] = cvtpk(f0, f1);
      }
      pl32swap(P[0], P[2]); pl32swap(P[1], P[3]);
      pl32swap(Q[0], Q[2]); pl32swap(Q[1], Q[3]);
      pk0[km * 4 + 0] = P[0]; pk0[km * 4 + 1] = P[1];
      pk0[km * 4 + 2] = P[2]; pk0[km * 4 + 3] = P[3];
      pk1[km * 4 + 0] = Q[0]; pk1[km * 4 + 1] = Q[1];
      pk1[km * 4 + 2] = Q[2]; pk1[km * 4 + 3] = Q[3];
    }
    bf16x8 p00 = frag4(pk0[0], pk0[1], pk0[2], pk0[3]);
    bf16x8 p01 = frag4(pk0[4], pk0[5], pk0[6], pk0[7]);
    bf16x8 p10 = frag4(pk1[0], pk1[1], pk1[2], pk1[3]);
    bf16x8 p11 = frag4(pk1[4], pk1[5], pk1[6], pk1[7]);

    bf16x8 g00 = *(const bf16x8*)(gtb + (0 * 32 + l31) * 128 + ((0  + hi * 16) ^ swz));
    bf16x8 g01 = *(const bf16x8*)(gtb + (0 * 32 + l31) * 128 + ((32 + hi * 16) ^ swz));
    bf16x8 g10 = *(const bf16x8*)(gtb + (1 * 32 + l31) * 128 + ((0  + hi * 16) ^ swz));
    bf16x8 g11 = *(const bf16x8*)(gtb + (1 * 32 + l31) * 128 + ((32 + hi * 16) ^ swz));
    __builtin_amdgcn_s_setprio(1);
    yacc[0] = mfma32(g00, p00, yacc[0]);
    yacc[1] = mfma32(g10, p00, yacc[1]);
    yacc[0] = mfma32(g01, p01, yacc[0]);
    yacc[1] = mfma32(g11, p01, yacc[1]);
    __builtin_amdgcn_s_setprio(0);
    bf16x8 g02 = *(const bf16x8*)(gtb + (0 * 32 + l31) * 128 + ((64 + hi * 16) ^ swz));
    bf16x8 g03 = *(const bf16x8*)(gtb + (0 * 32 + l31) * 128 + ((96 + hi * 16) ^ swz));
    bf16x8 g12 = *(const bf16x8*)(gtb + (1 * 32 + l31) * 128 + ((64 + hi * 16) ^ swz));
    bf16x8 g13 = *(const bf16x8*)(gtb + (1 * 32 + l31) * 128 + ((96 + hi * 16) ^ swz));
    __builtin_amdgcn_s_setprio(1);
    yacc[0] = mfma32(g02, p10, yacc[0]);
    yacc[1] = mfma32(g12, p10, yacc[1]);
    yacc[0] = mfma32(g03, p11, yacc[0]);
    yacc[1] = mfma32(g13, p11, yacc[1]);
    __builtin_amdgcn_s_setprio(0);

    // all my LDS reads retired; barrier → whole block done reading buf[mt&1];
    // only then overwrite it with tile mt+2 (loads stay async past the barrier)
    asm volatile("s_waitcnt lgkmcnt(0)" ::: "memory");
    __builtin_amdgcn_s_barrier();
    if (mt + 2 < MT) stage(mt + 2, mt & 1);
  }

  float Lp = Lpa + Lpb;
  Lp += __shfl_xor(Lp, 32);

  const size_t pbase = ((size_t)s * BB + b) * NN;
  if (hi == 0) Lq[pbase + nw + l31] = Lp;

  const size_t qg = pbase + nw + l31;
#pragma unroll
  for (int ci = 0; ci < 2; ++ci)
#pragma unroll
    for (int rg = 0; rg < 4; ++rg) {
      u16 o4[4];
#pragma unroll
      for (int j = 0; j < 4; ++j) o4[j] = f2bf(yacc[ci][rg * 4 + j]);
      *(unsigned long long*)(yp + qg * ICH + ci * 32 + 8 * rg + 4 * hi) =
          *(unsigned long long*)o4;
    }
}

// ---------------- Kernel 3: combine partials, out = W.y + Wb + x (R13 verbatim) -----
// grid: BB * (NN/32) = 512 blocks, 512 threads (8 waves, 16x16x32 MFMA)
__global__ __launch_bounds__(512) void out_kernel(
    const float* __restrict__ x, const float* __restrict__ Ww,
    const float* __restrict__ Wb, const u16* __restrict__ yp,
    const float* __restrict__ Lq, float* __restrict__ out)
{
  __shared__ float ysf[2][32][68];   // f32 half-sums, padded rows
  __shared__ float dens[2][32];
  const int t = threadIdx.x, lane = t & 63;
  const int wave = t >> 6;
  const int l15 = lane & 15, kq = lane >> 4;   // 16x16 fragment coords
  const int b  = blockIdx.x >> 7;
  const int n0 = (blockIdx.x & 127) << 5;

  {
    const int i8 = t & 7, sh = (t >> 3) & 1, n = t >> 4;
    float num[8];
#pragma unroll
    for (int j = 0; j < 8; ++j) num[j] = 0.f;
#pragma unroll
    for (int si = 0; si < 4; ++si) {
      const int s = sh * 4 + si;
      bf16x8 v = *(const bf16x8*)(yp + (((size_t)s * BB + b) * NN + n0 + n) * ICH + i8 * 8);
#pragma unroll
      for (int j = 0; j < 8; ++j) num[j] += bf2f((u16)v[j]);
    }
    *(float4*)&ysf[sh][n][i8 * 8]     = make_float4(num[0], num[1], num[2], num[3]);
    *(float4*)&ysf[sh][n][i8 * 8 + 4] = make_float4(num[4], num[5], num[6], num[7]);
    if (i8 == 0) {
      float den = 0.f;
#pragma unroll
      for (int si = 0; si < 4; ++si)
        den += Lq[((size_t)(sh * 4 + si) * BB + b) * NN + n0 + n];
      dens[sh][n] = den;
    }
  }
  __syncthreads();

  const int c0 = wave * 16;
  bf16x8 wfr[2];
#pragma unroll
  for (int kt = 0; kt < 2; ++kt) {
    const float* wp = Ww + (c0 + l15) * ICH + kt * 32 + kq * 8;
    float4 w0 = *(const float4*)wp, w1 = *(const float4*)(wp + 4);
    wfr[kt] = frag4(cvtpk(w0.x, w0.y), cvtpk(w0.z, w0.w),
                    cvtpk(w1.x, w1.y), cvtpk(w1.z, w1.w));
  }
#pragma unroll
  for (int nh = 0; nh < 2; ++nh) {
    const int n = nh * 16 + l15;
    const float rd = 1.f / (dens[0][n] + dens[1][n]);
    f32x4 acc = {0.f, 0.f, 0.f, 0.f};
#pragma unroll
    for (int kt = 0; kt < 2; ++kt) {
      const int base = kt * 32 + kq * 8;
      float4 a0 = *(const float4*)&ysf[0][n][base];
      float4 a1 = *(const float4*)&ysf[0][n][base + 4];
      float4 b0 = *(const float4*)&ysf[1][n][base];
      float4 b1 = *(const float4*)&ysf[1][n][base + 4];
      bf16x8 bfr = frag4(cvtpk((a0.x + b0.x) * rd, (a0.y + b0.y) * rd),
                         cvtpk((a0.z + b0.z) * rd, (a0.w + b0.w) * rd),
                         cvtpk((a1.x + b1.x) * rd, (a1.y + b1.y) * rd),
                         cvtpk((a1.z + b1.z) * rd, (a1.w + b1.w) * rd));
      acc = mfma16(wfr[kt], bfr, acc);
    }
#pragma unroll
    for (int reg = 0; reg < 4; ++reg) {
      const int c = c0 + kq * 4 + reg;
      size_t o = ((size_t)(b * CC + c) << 12) + n0 + nh * 16 + l15;
      out[o] = acc[reg] + Wb[c] + x[o];
    }
  }
}

extern "C" void kernel_launch(void* const* d_in, const int* in_sizes, int n_in,
                              void* d_out, int out_size, void* d_ws, size_t ws_size,
                              hipStream_t stream) {
  const float* x  = (const float*)d_in[0];
  const float* gw = (const float*)d_in[1];
  const float* gb = (const float*)d_in[2];
  const float* tw = (const float*)d_in[3];
  const float* tb = (const float*)d_in[4];
  const float* pw = (const float*)d_in[5];
  const float* pb = (const float*)d_in[6];
  const float* Ww = (const float*)d_in[7];
  const float* Wb = (const float*)d_in[8];
  float* out = (float*)d_out;

  char* ws = (char*)d_ws;
  u16*   th = (u16*)(ws);                      // 2MB
  u16*   ph = (u16*)(ws + (2ull << 20));       // 2MB
  u16*   gt = (u16*)(ws + (4ull << 20));       // 2MB
  u16*   yp = (u16*)(ws + (6ull << 20));       // SS*B*N*IC bf16 = 16MB
  float* Lq = (float*)(ws + (22ull << 20));    // SS*B*N f32 = 512KB

  proj_kernel<<<512, 384, 0, stream>>>(x, gw, gb, tw, tb, pw, pb, th, ph, gt);
  attn_kernel<<<BB * (NN / 128) * SS, 256, 0, stream>>>(th, ph, gt, yp, Lq);
  out_kernel<<<512, 512, 0, stream>>>(x, Ww, Wb, yp, Lq, out);
}